// Round 1
// baseline (55.074 us; speedup 1.0000x reference)
//
#include <hip/hip_runtime.h>
#include <cstdint>
#include <cstddef>
#include <algorithm>

// ---------------- problem constants ----------------
#define NROW 16      // only bn rows 0..15 are used by the outputs (n=16)
#define CTOT 384
#define HW   1024    // 32*32
#define KSEL 20
#define PSEL 96
#define NREM 76      // P - K
#define NUNSEL 1004  // HW - K

// Switch between JAX threefry_partitionable (modern default) and original.
#define USE_PARTITIONABLE 1

struct Perm76 { int p[NREM]; };

// ---------------- kernel A: fused dw3x3 + pw conv, partial over channel slice ----------------
// grid = NROW * split blocks, 256 threads. Block (r, s) handles channels
// [s*cpb, (s+1)*cpb) of image row r, accumulating the channel-summed 3x3 conv
// into a 32x32 partial plane written to ws.
__global__ __launch_bounds__(256) void pv_convA(
    const float* __restrict__ feat, const float* __restrict__ dw_w,
    const float* __restrict__ pw_w, float* __restrict__ partial,
    int split, int cpb)
{
  __shared__ float plane[HW];
  const int t  = threadIdx.x;
  const int r  = blockIdx.x / split;
  const int s  = blockIdx.x % split;
  const int c0 = s * cpb;
  const float* base = feat + ((size_t)r * CTOT + c0) * HW;
  const int x  = t & 31;
  const int y0 = t >> 5;
  float a0 = 0.f, a1 = 0.f, a2 = 0.f, a3 = 0.f;

  for (int c = 0; c < cpb; ++c) {
    // coalesced 16B/lane global load of the whole 32x32 plane
    const float4 v = reinterpret_cast<const float4*>(base + (size_t)c * HW)[t];
    const int cc = c0 + c;
    const float pw = pw_w[cc];
    const float w0 = dw_w[cc*9+0]*pw, w1 = dw_w[cc*9+1]*pw, w2 = dw_w[cc*9+2]*pw;
    const float w3 = dw_w[cc*9+3]*pw, w4 = dw_w[cc*9+4]*pw, w5 = dw_w[cc*9+5]*pw;
    const float w6 = dw_w[cc*9+6]*pw, w7 = dw_w[cc*9+7]*pw, w8 = dw_w[cc*9+8]*pw;
    __syncthreads();                     // prior iteration done reading plane
    reinterpret_cast<float4*>(plane)[t] = v;
    __syncthreads();                     // plane ready
    #pragma unroll
    for (int q = 0; q < 4; ++q) {
      const int y = y0 + q * 8;          // pixel index = t + q*256
      float acc = 0.f;
      if (y > 0) {
        const float* row = &plane[(y - 1) * 32];
        acc += (x > 0 ? row[x-1] : 0.f) * w0 + row[x] * w1 + (x < 31 ? row[x+1] : 0.f) * w2;
      }
      {
        const float* row = &plane[y * 32];
        acc += (x > 0 ? row[x-1] : 0.f) * w3 + row[x] * w4 + (x < 31 ? row[x+1] : 0.f) * w5;
      }
      if (y < 31) {
        const float* row = &plane[(y + 1) * 32];
        acc += (x > 0 ? row[x-1] : 0.f) * w6 + row[x] * w7 + (x < 31 ? row[x+1] : 0.f) * w8;
      }
      if      (q == 0) a0 += acc;
      else if (q == 1) a1 += acc;
      else if (q == 2) a2 += acc;
      else             a3 += acc;
    }
  }
  float* op = partial + (size_t)blockIdx.x * HW;
  op[t]       = a0;
  op[t + 256] = a1;
  op[t + 512] = a2;
  op[t + 768] = a3;
}

// ---------------- kernel B: reduce partials, top-20, selection, emit coords ----------------
// grid = NROW blocks, 256 threads. Output layout: x_out (16*96) then y_out (16*96), int32.
__global__ __launch_bounds__(256) void pv_selectB(
    const float* __restrict__ partial, int split, int* __restrict__ out, Perm76 perm)
{
  __shared__ float score[HW];
  __shared__ int   votes[KSEL];
  __shared__ int   maskv[HW];
  __shared__ int   offs[256];
  __shared__ int   unsel[NUNSEL];

  const int r = blockIdx.x;
  const int t = threadIdx.x;

  // 1) reduce channel-slice partials -> logits (ordering-equivalent to sigmoid scores)
  #pragma unroll
  for (int q = 0; q < 4; ++q) {
    const int i = t + q * 256;
    float sum = 0.f;
    for (int s = 0; s < split; ++s)
      sum += partial[((size_t)(r * split + s)) * HW + i];
    score[i] = sum;
  }
  maskv[t] = 0; maskv[t + 256] = 0; maskv[t + 512] = 0; maskv[t + 768] = 0;
  __syncthreads();

  // 2) wave-0 iterative top-20. Key = monotone f32 map << 32 | (1023-idx):
  //    larger value wins; ties -> smaller index wins (matches jax.lax.top_k).
  if (t < 64) {
    unsigned long long keys[16];
    #pragma unroll
    for (int j = 0; j < 16; ++j) {
      const int i = t * 16 + j;
      const uint32_t b = __float_as_uint(score[i]);
      const uint32_t m = (b & 0x80000000u) ? ~b : (b | 0x80000000u);
      keys[j] = ((unsigned long long)m << 32) | (uint32_t)(1023 - i);
    }
    for (int k = 0; k < KSEL; ++k) {
      unsigned long long best = 0ull;
      #pragma unroll
      for (int j = 0; j < 16; ++j) best = keys[j] > best ? keys[j] : best;
      #pragma unroll
      for (int off = 32; off; off >>= 1) {
        unsigned long long o = __shfl_xor(best, off);
        if (o > best) best = o;
      }
      #pragma unroll
      for (int j = 0; j < 16; ++j) if (keys[j] == best) keys[j] = 0ull;  // keys are unique
      if (t == 0) votes[k] = 1023 - (int)(best & 1023u);
    }
  }
  __syncthreads();

  // 3) selected coords + mask
  if (t < KSEL) {
    const int idx = votes[t];
    maskv[idx] = 1;
    int xx = idx & 31, yy = idx >> 5;
    if (xx < 1) xx = 1;               // clip(.,1,31); upper bound can't trigger
    if (yy < 1) yy = 1;
    out[r * PSEL + t]                 = xx;
    out[NROW * PSEL + r * PSEL + t]   = yy;
  }
  __syncthreads();

  // 4) unselected indices ascending via prefix sum over !mask
  int cnt = 0;
  #pragma unroll
  for (int j = 0; j < 4; ++j) cnt += (maskv[t * 4 + j] == 0);
  offs[t] = cnt;
  __syncthreads();
  if (t == 0) {
    int run = 0;
    for (int i = 0; i < 256; ++i) { const int c = offs[i]; offs[i] = run; run += c; }
  }
  __syncthreads();
  int pos = offs[t];
  #pragma unroll
  for (int j = 0; j < 4; ++j) {
    const int i = t * 4 + j;
    if (!maskv[i]) unsel[pos++] = i;
  }
  __syncthreads();

  // 5) random remaining via fixed permutation
  if (t < NREM) {
    const int u = unsel[perm.p[t]];
    int xx = u & 31, yy = u >> 5;
    if (xx < 1) xx = 1;
    if (yy < 1) yy = 1;
    out[r * PSEL + KSEL + t]               = xx;
    out[NROW * PSEL + r * PSEL + KSEL + t] = yy;
  }
}

// ---------------- host: JAX threefry2x32 reimplementation ----------------
static inline uint32_t rotl32(uint32_t v, uint32_t n) { return (v << n) | (v >> (32 - n)); }

static void tf2x32(uint32_t k0, uint32_t k1, uint32_t x0, uint32_t x1,
                   uint32_t* o0, uint32_t* o1)
{
  const uint32_t ks[3] = { k0, k1, k0 ^ k1 ^ 0x1BD11BDAu };
  static const uint32_t rot[2][4] = { {13, 15, 26, 6}, {17, 29, 16, 24} };
  x0 += ks[0]; x1 += ks[1];
  for (int i = 0; i < 5; ++i) {
    const uint32_t* rr = rot[i & 1];
    for (int j = 0; j < 4; ++j) { x0 += x1; x1 = rotl32(x1, rr[j]); x1 ^= x0; }
    x0 += ks[(i + 1) % 3];
    x1 += ks[(i + 2) % 3] + (uint32_t)(i + 1);
  }
  *o0 = x0; *o1 = x1;
}

// perm = jax.random.permutation(jax.random.key(42), 1004)[:76]
static void compute_perm(int* perm_out)
{
  uint32_t bits[NUNSEL];
#if USE_PARTITIONABLE
  // split: subkey = both outputs of tf(key, (0,1)); bits[i] = o0^o1 of tf(subkey,(0,i))
  uint32_t sk0, sk1;
  { uint32_t o0, o1; tf2x32(0u, 42u, 0u, 1u, &o0, &o1); sk0 = o0; sk1 = o1; }
  for (int i = 0; i < NUNSEL; ++i) {
    uint32_t o0, o1; tf2x32(sk0, sk1, 0u, (uint32_t)i, &o0, &o1);
    bits[i] = o0 ^ o1;
  }
#else
  // original: split on counts [0,1,2,3]; subkey = (tf(key,(0,2)).o1, tf(key,(1,3)).o1)
  uint32_t sk0, sk1;
  { uint32_t a0, b0, a1, b1;
    tf2x32(0u, 42u, 0u, 2u, &a0, &b0);
    tf2x32(0u, 42u, 1u, 3u, &a1, &b1);
    sk0 = b0; sk1 = b1; }
  for (int i = 0; i < 502; ++i) {
    uint32_t o0, o1; tf2x32(sk0, sk1, (uint32_t)i, (uint32_t)(502 + i), &o0, &o1);
    bits[i] = o0; bits[502 + i] = o1;
  }
#endif
  int idx[NUNSEL];
  for (int i = 0; i < NUNSEL; ++i) idx[i] = i;
  std::stable_sort(idx, idx + NUNSEL, [&](int a, int b) { return bits[a] < bits[b]; });
  for (int j = 0; j < NREM; ++j) perm_out[j] = idx[j];
}

extern "C" void kernel_launch(void* const* d_in, const int* in_sizes, int n_in,
                              void* d_out, int out_size, void* d_ws, size_t ws_size,
                              hipStream_t stream)
{
  (void)in_sizes; (void)n_in; (void)out_size;
  const float* feat = (const float*)d_in[0];
  const float* dw_w = (const float*)d_in[1];
  // d_in[2] = dw_b (zeros; constant shift, ordering-irrelevant)
  const float* pw_w = (const float*)d_in[3];
  // d_in[4] = pw_b (constant shift, ordering-irrelevant)
  int*   out     = (int*)d_out;
  float* partial = (float*)d_ws;

  // channel-split factor sized to workspace (16*split*4KB needed); divides 384.
  int split = 16;
  while (split > 1 && (size_t)NROW * split * HW * sizeof(float) > ws_size) split >>= 1;
  const int cpb = CTOT / split;

  Perm76 perm;
  compute_perm(perm.p);   // deterministic host compute; baked into graph as kernel arg

  pv_convA<<<NROW * split, 256, 0, stream>>>(feat, dw_w, pw_w, partial, split, cpb);
  pv_selectB<<<NROW, 256, 0, stream>>>(partial, split, out, perm);
}

// Round 2
// 29.853 us; speedup vs baseline: 1.8448x; 1.8448x over previous
//
#include <hip/hip_runtime.h>
#include <cstdint>
#include <cstddef>
#include <algorithm>

// ---------------- problem constants ----------------
#define NROW 16      // only bn rows 0..15 feed the outputs (n=16)
#define CTOT 384
#define HW   1024    // 32*32
#define KSEL 20
#define PSEL 96
#define NREM 76      // P - K
#define NUNSEL 1004  // HW - K

#define CPB   8                  // channels per block (kernel A)
#define SPLIT (CTOT / CPB)       // 48
#define SCALE 4294967296.0f      // 2^32 fixed-point scale for deterministic i64 accumulation

struct Perm76 { int p[NREM]; };

// ---------------- kernel A: fused dw3x3+pw conv, i64 fixed-point atomic accumulate ----------------
// grid = NROW*SPLIT (768) blocks, 256 threads. Block (r,s) handles channels [s*CPB,(s+1)*CPB)
// of image r. All CPB planes staged in LDS up front (1 sync), zero-padded rows 0/33.
__global__ __launch_bounds__(256) void pv_convA(
    const float* __restrict__ feat, const float* __restrict__ dw_w,
    const float* __restrict__ pw_w, unsigned long long* __restrict__ score)
{
  __shared__ float plane[CPB][34 * 32];
  const int t = threadIdx.x;
  const int r = blockIdx.x & (NROW - 1);
  const int s = blockIdx.x >> 4;           // blockIdx / 16
  const int c0 = s * CPB;
  const float* base = feat + ((size_t)r * CTOT + c0) * HW;

  // issue all global loads first (max MLP)
  float4 v[CPB];
  #pragma unroll
  for (int c = 0; c < CPB; ++c)
    v[c] = reinterpret_cast<const float4*>(base + (size_t)c * HW)[t];

  // zero the pad rows (rows 0 and 33 of each plane)
  #pragma unroll
  for (int z = t; z < CPB * 64; z += 256) {
    const int c = z >> 6, k = z & 63;
    plane[c][(k & 32 ? 33 : 0) * 32 + (k & 31)] = 0.f;
  }

  // park loaded planes: thread t's float4 covers pixels 4t..4t+3 (row t>>3, col (t&7)*4)
  {
    const int py = t >> 3, px = (t & 7) * 4;
    #pragma unroll
    for (int c = 0; c < CPB; ++c)
      *reinterpret_cast<float4*>(&plane[c][(py + 1) * 32 + px]) = v[c];
  }
  __syncthreads();

  // per-channel fused weights (uniform scalar loads)
  float w[CPB][9];
  #pragma unroll
  for (int c = 0; c < CPB; ++c) {
    const float pw = pw_w[c0 + c];
    #pragma unroll
    for (int i = 0; i < 9; ++i) w[c][i] = dw_w[(c0 + c) * 9 + i] * pw;
  }

  const int x = t & 31;
  const int y0 = (t >> 5) * 4;             // 0,4,...,28
  const float mL = (x > 0) ? 1.f : 0.f;
  const float mR = (x < 31) ? 1.f : 0.f;
  const int xl = (x > 0) ? x - 1 : 0;
  const int xr = (x < 31) ? x + 1 : 31;

  float a0 = 0.f, a1 = 0.f, a2 = 0.f, a3 = 0.f;
  #pragma unroll
  for (int c = 0; c < CPB; ++c) {
    // fold x-boundary masks into the column weights
    const float wl0 = w[c][0] * mL, wc0 = w[c][1], wr0 = w[c][2] * mR;
    const float wl1 = w[c][3] * mL, wc1 = w[c][4], wr1 = w[c][5] * mR;
    const float wl2 = w[c][6] * mL, wc2 = w[c][7], wr2 = w[c][8] * mR;
    float L[6], C[6], R[6];
    #pragma unroll
    for (int j = 0; j < 6; ++j) {          // padded rows y0 .. y0+5
      const float* row = &plane[c][(y0 + j) * 32];
      L[j] = row[xl]; C[j] = row[x]; R[j] = row[xr];
    }
    #pragma unroll
    for (int q = 0; q < 4; ++q) {
      float acc = L[q]   * wl0 + C[q]   * wc0 + R[q]   * wr0
                + L[q+1] * wl1 + C[q+1] * wc1 + R[q+1] * wr1
                + L[q+2] * wl2 + C[q+2] * wc2 + R[q+2] * wr2;
      if      (q == 0) a0 += acc;
      else if (q == 1) a1 += acc;
      else if (q == 2) a2 += acc;
      else             a3 += acc;
    }
  }

  unsigned long long* sc = score + (size_t)r * HW;
  sc += y0 * 32 + x;
  atomicAdd(&sc[0],      (unsigned long long)(long long)llrintf(a0 * SCALE));
  atomicAdd(&sc[32],     (unsigned long long)(long long)llrintf(a1 * SCALE));
  atomicAdd(&sc[64],     (unsigned long long)(long long)llrintf(a2 * SCALE));
  atomicAdd(&sc[96],     (unsigned long long)(long long)llrintf(a3 * SCALE));
}

// ---------------- kernel B: top-20 + selection + emit coords ----------------
// grid = NROW blocks, 256 threads. Output: x_out (16*96) then y_out (16*96), int32.
__global__ __launch_bounds__(256) void pv_selectB(
    const unsigned long long* __restrict__ score, int* __restrict__ out, Perm76 perm)
{
  __shared__ unsigned long long keysh[HW];
  __shared__ int   votes[KSEL];
  __shared__ int   maskv[HW];
  __shared__ int   wsum[4];
  __shared__ int   unsel[NUNSEL];

  const int r = blockIdx.x;
  const int t = threadIdx.x;
  const unsigned long long* sc = score + (size_t)r * HW;

  // 1) load fixed-point sums -> monotone sortable keys (value<<.. | 1023-idx)
  #pragma unroll
  for (int q = 0; q < 4; ++q) {
    const int i = t + q * 256;
    const unsigned long long u = sc[i] + 0x8000000000000000ull;  // signed->monotone unsigned
    keysh[i] = (u & ~1023ull) | (unsigned long long)(1023 - i);
  }
  maskv[t] = 0; maskv[t + 256] = 0; maskv[t + 512] = 0; maskv[t + 768] = 0;
  __syncthreads();

  // 2) wave-0 iterative top-20 (keys unique: low bits are the index)
  if (t < 64) {
    unsigned long long keys[16];
    #pragma unroll
    for (int j = 0; j < 16; ++j) keys[j] = keysh[t * 16 + j];
    for (int k = 0; k < KSEL; ++k) {
      unsigned long long best = 0ull;
      #pragma unroll
      for (int j = 0; j < 16; ++j) best = keys[j] > best ? keys[j] : best;
      #pragma unroll
      for (int off = 32; off; off >>= 1) {
        const unsigned long long o = __shfl_xor(best, off);
        if (o > best) best = o;
      }
      #pragma unroll
      for (int j = 0; j < 16; ++j) if (keys[j] == best) keys[j] = 0ull;
      if (t == 0) votes[k] = 1023 - (int)(best & 1023ull);
    }
  }
  __syncthreads();

  // 3) selected coords + mask
  if (t < KSEL) {
    const int idx = votes[t];
    maskv[idx] = 1;
    int xx = idx & 31, yy = idx >> 5;
    if (xx < 1) xx = 1;
    if (yy < 1) yy = 1;
    out[r * PSEL + t]               = xx;
    out[NROW * PSEL + r * PSEL + t] = yy;
  }
  __syncthreads();

  // 4) unselected indices ascending via parallel prefix over !mask
  int cnt = 0;
  #pragma unroll
  for (int j = 0; j < 4; ++j) cnt += (maskv[t * 4 + j] == 0);
  const int lane = t & 63, wv = t >> 6;
  int inc = cnt;
  #pragma unroll
  for (int d = 1; d < 64; d <<= 1) {
    const int o = __shfl_up(inc, d);
    if (lane >= d) inc += o;
  }
  if (lane == 63) wsum[wv] = inc;
  __syncthreads();
  int basep = 0;
  for (int i = 0; i < 4; ++i) if (i < wv) basep += wsum[i];
  int pos = basep + inc - cnt;             // exclusive prefix
  #pragma unroll
  for (int j = 0; j < 4; ++j) {
    const int i = t * 4 + j;
    if (!maskv[i]) unsel[pos++] = i;
  }
  __syncthreads();

  // 5) random remaining via fixed permutation
  if (t < NREM) {
    const int u = unsel[perm.p[t]];
    int xx = u & 31, yy = u >> 5;
    if (xx < 1) xx = 1;
    if (yy < 1) yy = 1;
    out[r * PSEL + KSEL + t]               = xx;
    out[NROW * PSEL + r * PSEL + KSEL + t] = yy;
  }
}

// ---------------- host: JAX threefry2x32 (partitionable) ----------------
static inline uint32_t rotl32(uint32_t v, uint32_t n) { return (v << n) | (v >> (32 - n)); }

static void tf2x32(uint32_t k0, uint32_t k1, uint32_t x0, uint32_t x1,
                   uint32_t* o0, uint32_t* o1)
{
  const uint32_t ks[3] = { k0, k1, k0 ^ k1 ^ 0x1BD11BDAu };
  static const uint32_t rot[2][4] = { {13, 15, 26, 6}, {17, 29, 16, 24} };
  x0 += ks[0]; x1 += ks[1];
  for (int i = 0; i < 5; ++i) {
    const uint32_t* rr = rot[i & 1];
    for (int j = 0; j < 4; ++j) { x0 += x1; x1 = rotl32(x1, rr[j]); x1 ^= x0; }
    x0 += ks[(i + 1) % 3];
    x1 += ks[(i + 2) % 3] + (uint32_t)(i + 1);
  }
  *o0 = x0; *o1 = x1;
}

// perm = jax.random.permutation(jax.random.key(42), 1004)[:76]  (threefry_partitionable)
static void compute_perm(int* perm_out)
{
  uint32_t bits[NUNSEL];
  uint32_t sk0, sk1;
  { uint32_t o0, o1; tf2x32(0u, 42u, 0u, 1u, &o0, &o1); sk0 = o0; sk1 = o1; }
  for (int i = 0; i < NUNSEL; ++i) {
    uint32_t o0, o1; tf2x32(sk0, sk1, 0u, (uint32_t)i, &o0, &o1);
    bits[i] = o0 ^ o1;
  }
  int idx[NUNSEL];
  for (int i = 0; i < NUNSEL; ++i) idx[i] = i;
  std::stable_sort(idx, idx + NUNSEL, [&](int a, int b) { return bits[a] < bits[b]; });
  for (int j = 0; j < NREM; ++j) perm_out[j] = idx[j];
}

extern "C" void kernel_launch(void* const* d_in, const int* in_sizes, int n_in,
                              void* d_out, int out_size, void* d_ws, size_t ws_size,
                              hipStream_t stream)
{
  (void)in_sizes; (void)n_in; (void)out_size; (void)ws_size;
  const float* feat = (const float*)d_in[0];
  const float* dw_w = (const float*)d_in[1];
  // d_in[2] = dw_b (zeros; constant shift, ordering-irrelevant)
  const float* pw_w = (const float*)d_in[3];
  // d_in[4] = pw_b (constant shift, ordering-irrelevant)
  int* out = (int*)d_out;
  unsigned long long* score = (unsigned long long*)d_ws;   // NROW*HW i64 = 128 KB

  Perm76 perm;
  compute_perm(perm.p);   // deterministic host compute, baked in as kernel arg

  hipMemsetAsync(score, 0, (size_t)NROW * HW * sizeof(unsigned long long), stream);
  pv_convA<<<NROW * SPLIT, 256, 0, stream>>>(feat, dw_w, pw_w, score);
  pv_selectB<<<NROW, 256, 0, stream>>>(score, out, perm);
}

// Round 3
// 24.457 us; speedup vs baseline: 2.2519x; 1.2206x over previous
//
#include <hip/hip_runtime.h>
#include <cstdint>
#include <cstddef>
#include <algorithm>

// ---------------- problem constants ----------------
#define NROW 16      // only bn rows 0..15 feed the outputs (n=16)
#define CTOT 384
#define HW   1024    // 32*32
#define KSEL 20
#define PSEL 96
#define NREM 76      // P - K
#define NUNSEL 1004  // HW - K

#define CPB   12                 // channels per block (kernel A)
#define SPLIT (CTOT / CPB)       // 32
#define RSTR  40                 // padded LDS row stride (floats): [pad3|1|32 data|1|pad3]
#define PROW  34                 // padded rows: zero, 32 data, zero

struct Perm76 { int p[NREM]; };

// ---------------- kernel A: fused dw3x3+pw conv -> private partial planes ----------------
// grid = NROW*SPLIT (512) blocks, 256 threads, 2 blocks/CU. Block (r,s) handles channels
// [s*CPB,(s+1)*CPB) of image r; writes a 4 KB f32 partial plane (no atomics, no init).
__global__ __launch_bounds__(256) void pv_convA(
    const float* __restrict__ feat, const float* __restrict__ dw_w,
    const float* __restrict__ pw_w, float* __restrict__ partial)
{
  __shared__ float plane[CPB][PROW * RSTR];   // 65,280 B
  __shared__ float redsum[2][HW];             //  8,192 B
  const int t  = threadIdx.x;
  const int r  = blockIdx.x & (NROW - 1);
  const int s  = blockIdx.x >> 4;
  const int c0 = s * CPB;
  const float* base = feat + ((size_t)r * CTOT + c0) * HW;

  // issue all plane loads first (max MLP); 48 KB/block, 25 MB total
  float4 v[CPB];
  #pragma unroll
  for (int c = 0; c < CPB; ++c)
    v[c] = reinterpret_cast<const float4*>(base + (size_t)c * HW)[t];

  // per-thread fused weights for the 6 channels this thread will process
  const int hh = t >> 7;                      // channel parity (thread half)
  float wreg[CPB / 2][9];
  #pragma unroll
  for (int p = 0; p < CPB / 2; ++p) {
    const int cg = c0 + 2 * p + hh;
    const float pw = pw_w[cg];
    #pragma unroll
    for (int i = 0; i < 9; ++i) wreg[p][i] = dw_w[cg * 9 + i] * pw;
  }

  // zero the pad cells: rows 0,33 full (80) + cols 3,36 rows 1..32 (64) = 144/plane
  for (int z = t; z < CPB * 144; z += 256) {
    const int c = z / 144, k = z % 144;
    int row, col;
    if (k < 80) { row = (k < 40) ? 0 : 33; col = k - (k < 40 ? 0 : 40); }
    else        { const int k2 = k - 80; col = (k2 < 32) ? 3 : 36; row = 1 + (k2 & 31); }
    plane[c][row * RSTR + col] = 0.f;
  }

  // park loaded planes (16B-aligned: data cols start at 4)
  {
    const int row = (t >> 3) + 1, col4 = ((t & 7) << 2) + 4;
    #pragma unroll
    for (int c = 0; c < CPB; ++c)
      *reinterpret_cast<float4*>(&plane[c][row * RSTR + col4]) = v[c];
  }
  __syncthreads();

  // compute: 128 threads per channel, 8-pixel vertical strip each; 2 channels in flight
  const int h     = t & 127;
  const int col   = h & 31;
  const int rbase = (h >> 5) * 8;             // first padded input row of this strip

  float acc[8];
  #pragma unroll
  for (int j = 0; j < 8; ++j) acc[j] = 0.f;

  #pragma unroll
  for (int p = 0; p < CPB / 2; ++p) {
    const int cc = 2 * p + hh;
    const float w0 = wreg[p][0], w1 = wreg[p][1], w2 = wreg[p][2];
    const float w3 = wreg[p][3], w4 = wreg[p][4], w5 = wreg[p][5];
    const float w6 = wreg[p][6], w7 = wreg[p][7], w8 = wreg[p][8];
    const float* pl = plane[cc];
    float L[10], C[10], R[10];
    #pragma unroll
    for (int m = 0; m < 10; ++m) {            // padded rows rbase..rbase+9
      const float* rw = &pl[(rbase + m) * RSTR + 4 + col];
      L[m] = rw[-1]; C[m] = rw[0]; R[m] = rw[1];
    }
    #pragma unroll
    for (int j = 0; j < 8; ++j) {
      acc[j] += L[j]     * w0 + C[j]     * w1 + R[j]     * w2
              + L[j + 1] * w3 + C[j + 1] * w4 + R[j + 1] * w5
              + L[j + 2] * w6 + C[j + 2] * w7 + R[j + 2] * w8;
    }
  }

  // combine the two channel-parity halves and store the partial plane
  #pragma unroll
  for (int j = 0; j < 8; ++j)
    redsum[hh][(rbase + j) * 32 + col] = acc[j];
  __syncthreads();
  const float4 a = reinterpret_cast<const float4*>(redsum[0])[t];
  const float4 b = reinterpret_cast<const float4*>(redsum[1])[t];
  float4 o; o.x = a.x + b.x; o.y = a.y + b.y; o.z = a.z + b.z; o.w = a.w + b.w;
  reinterpret_cast<float4*>(partial + (size_t)blockIdx.x * HW)[t] = o;
}

// ---------------- kernel B: reduce partials, top-20, selection, emit coords ----------------
// grid = NROW blocks, 256 threads. Output: x_out (16*96) then y_out (16*96), int32.
__global__ __launch_bounds__(256) void pv_selectB(
    const float* __restrict__ partial, int* __restrict__ out, Perm76 perm)
{
  __shared__ unsigned long long keysh[HW];
  __shared__ int votes[KSEL];
  __shared__ int maskv[HW];
  __shared__ int wsum[4];
  __shared__ int unsel[NUNSEL];

  const int r = blockIdx.x;
  const int t = threadIdx.x;

  // 1) reduce the 32 channel-slice partials (L2/L3-resident, 128 KB/block)
  float4 acc4 = make_float4(0.f, 0.f, 0.f, 0.f);
  for (int s = 0; s < SPLIT; ++s) {
    const float4 v = reinterpret_cast<const float4*>(partial + ((size_t)(s * NROW + r)) * HW)[t];
    acc4.x += v.x; acc4.y += v.y; acc4.z += v.z; acc4.w += v.w;
  }
  // monotone sortable keys: larger score wins, ties -> smaller index wins
  {
    const float sv[4] = { acc4.x, acc4.y, acc4.z, acc4.w };
    #pragma unroll
    for (int q = 0; q < 4; ++q) {
      const int i = 4 * t + q;
      const uint32_t bbit = __float_as_uint(sv[q]);
      const uint32_t m = (bbit & 0x80000000u) ? ~bbit : (bbit | 0x80000000u);
      keysh[i] = ((unsigned long long)m << 32) | (uint32_t)(1023 - i);
    }
  }
  maskv[t] = 0; maskv[t + 256] = 0; maskv[t + 512] = 0; maskv[t + 768] = 0;
  __syncthreads();

  // 2) wave-0 iterative top-20 (keys unique: low bits are the index)
  if (t < 64) {
    unsigned long long keys[16];
    #pragma unroll
    for (int j = 0; j < 16; ++j) keys[j] = keysh[t * 16 + j];
    for (int k = 0; k < KSEL; ++k) {
      unsigned long long best = 0ull;
      #pragma unroll
      for (int j = 0; j < 16; ++j) best = keys[j] > best ? keys[j] : best;
      #pragma unroll
      for (int off = 32; off; off >>= 1) {
        const unsigned long long o = __shfl_xor(best, off);
        if (o > best) best = o;
      }
      #pragma unroll
      for (int j = 0; j < 16; ++j) if (keys[j] == best) keys[j] = 0ull;
      if (t == 0) votes[k] = 1023 - (int)(best & 1023ull);
    }
  }
  __syncthreads();

  // 3) selected coords + mask
  if (t < KSEL) {
    const int idx = votes[t];
    maskv[idx] = 1;
    int xx = idx & 31, yy = idx >> 5;
    if (xx < 1) xx = 1;
    if (yy < 1) yy = 1;
    out[r * PSEL + t]               = xx;
    out[NROW * PSEL + r * PSEL + t] = yy;
  }
  __syncthreads();

  // 4) unselected indices ascending via shfl prefix over !mask
  int cnt = 0;
  #pragma unroll
  for (int j = 0; j < 4; ++j) cnt += (maskv[t * 4 + j] == 0);
  const int lane = t & 63, wv = t >> 6;
  int inc = cnt;
  #pragma unroll
  for (int d = 1; d < 64; d <<= 1) {
    const int o = __shfl_up(inc, d);
    if (lane >= d) inc += o;
  }
  if (lane == 63) wsum[wv] = inc;
  __syncthreads();
  int basep = 0;
  for (int i = 0; i < 4; ++i) if (i < wv) basep += wsum[i];
  int pos = basep + inc - cnt;               // exclusive prefix
  #pragma unroll
  for (int j = 0; j < 4; ++j) {
    const int i = t * 4 + j;
    if (!maskv[i]) unsel[pos++] = i;
  }
  __syncthreads();

  // 5) random remaining via fixed permutation
  if (t < NREM) {
    const int u = unsel[perm.p[t]];
    int xx = u & 31, yy = u >> 5;
    if (xx < 1) xx = 1;
    if (yy < 1) yy = 1;
    out[r * PSEL + KSEL + t]               = xx;
    out[NROW * PSEL + r * PSEL + KSEL + t] = yy;
  }
}

// ---------------- host: JAX threefry2x32 (partitionable) ----------------
static inline uint32_t rotl32(uint32_t v, uint32_t n) { return (v << n) | (v >> (32 - n)); }

static void tf2x32(uint32_t k0, uint32_t k1, uint32_t x0, uint32_t x1,
                   uint32_t* o0, uint32_t* o1)
{
  const uint32_t ks[3] = { k0, k1, k0 ^ k1 ^ 0x1BD11BDAu };
  static const uint32_t rot[2][4] = { {13, 15, 26, 6}, {17, 29, 16, 24} };
  x0 += ks[0]; x1 += ks[1];
  for (int i = 0; i < 5; ++i) {
    const uint32_t* rr = rot[i & 1];
    for (int j = 0; j < 4; ++j) { x0 += x1; x1 = rotl32(x1, rr[j]); x1 ^= x0; }
    x0 += ks[(i + 1) % 3];
    x1 += ks[(i + 2) % 3] + (uint32_t)(i + 1);
  }
  *o0 = x0; *o1 = x1;
}

// perm = jax.random.permutation(jax.random.key(42), 1004)[:76]  (threefry_partitionable)
static void compute_perm(int* perm_out)
{
  uint32_t bits[NUNSEL];
  uint32_t sk0, sk1;
  { uint32_t o0, o1; tf2x32(0u, 42u, 0u, 1u, &o0, &o1); sk0 = o0; sk1 = o1; }
  for (int i = 0; i < NUNSEL; ++i) {
    uint32_t o0, o1; tf2x32(sk0, sk1, 0u, (uint32_t)i, &o0, &o1);
    bits[i] = o0 ^ o1;
  }
  int idx[NUNSEL];
  for (int i = 0; i < NUNSEL; ++i) idx[i] = i;
  std::stable_sort(idx, idx + NUNSEL, [&](int a, int b) { return bits[a] < bits[b]; });
  for (int j = 0; j < NREM; ++j) perm_out[j] = idx[j];
}

extern "C" void kernel_launch(void* const* d_in, const int* in_sizes, int n_in,
                              void* d_out, int out_size, void* d_ws, size_t ws_size,
                              hipStream_t stream)
{
  (void)in_sizes; (void)n_in; (void)out_size; (void)ws_size;
  const float* feat = (const float*)d_in[0];
  const float* dw_w = (const float*)d_in[1];
  // d_in[2] = dw_b (zeros; constant shift, ordering-irrelevant)
  const float* pw_w = (const float*)d_in[3];
  // d_in[4] = pw_b (constant shift, ordering-irrelevant)
  int*   out     = (int*)d_out;
  float* partial = (float*)d_ws;             // NROW*SPLIT*HW f32 = 2 MB, fully rewritten

  Perm76 perm;
  compute_perm(perm.p);                      // deterministic host compute, kernel-arg baked

  pv_convA<<<NROW * SPLIT, 256, 0, stream>>>(feat, dw_w, pw_w, partial);
  pv_selectB<<<NROW, 256, 0, stream>>>(partial, out, perm);
}

// Round 4
// 18.934 us; speedup vs baseline: 2.9087x; 1.2917x over previous
//
#include <hip/hip_runtime.h>
#include <cstdint>
#include <cstddef>
#include <algorithm>

// ---------------- problem constants ----------------
#define NROW 16      // only bn rows 0..15 feed the outputs (n=16)
#define CTOT 384
#define HW   1024    // 32*32
#define KSEL 20
#define PSEL 96
#define NREM 76      // P - K
#define NUNSEL 1004  // HW - K

#define CPB   6                  // channels per block (kernel A)
#define SPLIT (CTOT / CPB)       // 64
#define RSTR  40                 // padded LDS row stride (floats): [pad3|halo|32 data|halo|pad3]
#define PROW  34                 // padded rows: zero, 32 data, zero

struct Perm76 { int p[NREM]; };

// ---------------- kernel A: fused dw3x3+pw conv -> private partial planes ----------------
// grid = NROW*SPLIT (1024) blocks = exactly 4 blocks/CU (16 waves/CU). Block (r,s) handles
// channels [s*CPB,(s+1)*CPB) of image r; writes a 4 KB f32 partial plane.
__global__ __launch_bounds__(256) void pv_convA(
    const float* __restrict__ feat, const float* __restrict__ dw_w,
    const float* __restrict__ pw_w, float* __restrict__ partial)
{
  __shared__ float plane[CPB][PROW * RSTR];   // 32,640 B
  __shared__ float redsum[HW];                //  4,096 B  -> 36.7 KB total, 4 blocks/CU
  const int t  = threadIdx.x;
  const int r  = blockIdx.x & (NROW - 1);
  const int s  = blockIdx.x >> 4;
  const int c0 = s * CPB;
  const float* base = feat + ((size_t)r * CTOT + c0) * HW;

  // issue all plane loads first (max MLP); 24 KB/block, 25 MB total
  float4 v[CPB];
  #pragma unroll
  for (int c = 0; c < CPB; ++c)
    v[c] = reinterpret_cast<const float4*>(base + (size_t)c * HW)[t];

  // per-thread fused weights for the CPB/2 channels this thread-half processes
  const int hh = t >> 7;                      // channel parity (thread half)
  float wreg[CPB / 2][9];
  #pragma unroll
  for (int p = 0; p < CPB / 2; ++p) {
    const int cg = c0 + 2 * p + hh;
    const float pw = pw_w[cg];
    #pragma unroll
    for (int i = 0; i < 9; ++i) wreg[p][i] = dw_w[cg * 9 + i] * pw;
  }

  // zero pad cells: rows 0,33 full (80) + halo cols 3,36 rows 1..32 (64) = 144/plane
  for (int z = t; z < CPB * 144; z += 256) {
    const int c = z / 144, k = z % 144;
    int row, col;
    if (k < 80) { row = (k < 40) ? 0 : 33; col = k - (k < 40 ? 0 : 40); }
    else        { const int k2 = k - 80; col = (k2 < 32) ? 3 : 36; row = 1 + (k2 & 31); }
    plane[c][row * RSTR + col] = 0.f;
  }

  // park loaded planes (16B-aligned: data cols start at padded col 4)
  {
    const int row = (t >> 3) + 1, col4 = ((t & 7) << 2) + 4;
    #pragma unroll
    for (int c = 0; c < CPB; ++c)
      *reinterpret_cast<float4*>(&plane[c][row * RSTR + col4]) = v[c];
  }
  __syncthreads();

  // compute: 128 threads per channel-half, 8-pixel vertical strip each
  const int h     = t & 127;
  const int col   = h & 31;
  const int rbase = (h >> 5) * 8;             // 0,8,16,24

  float acc[8];
  #pragma unroll
  for (int j = 0; j < 8; ++j) acc[j] = 0.f;

  #pragma unroll
  for (int p = 0; p < CPB / 2; ++p) {
    const int cc = 2 * p + hh;
    const float w0 = wreg[p][0], w1 = wreg[p][1], w2 = wreg[p][2];
    const float w3 = wreg[p][3], w4 = wreg[p][4], w5 = wreg[p][5];
    const float w6 = wreg[p][6], w7 = wreg[p][7], w8 = wreg[p][8];
    const float* pl = plane[cc];
    float L[10], C[10], R[10];
    #pragma unroll
    for (int m = 0; m < 10; ++m) {            // padded rows rbase..rbase+9
      const float* rw = &pl[(rbase + m) * RSTR + 4 + col];
      L[m] = rw[-1]; C[m] = rw[0]; R[m] = rw[1];
    }
    #pragma unroll
    for (int j = 0; j < 8; ++j) {
      acc[j] += L[j]     * w0 + C[j]     * w1 + R[j]     * w2
              + L[j + 1] * w3 + C[j + 1] * w4 + R[j + 1] * w5
              + L[j + 2] * w6 + C[j + 2] * w7 + R[j + 2] * w8;
    }
  }

  // combine halves through one LDS buffer, then coalesced float4 store
  if (hh == 1) {
    #pragma unroll
    for (int j = 0; j < 8; ++j) redsum[(rbase + j) * 32 + col] = acc[j];
  }
  __syncthreads();
  if (hh == 0) {
    #pragma unroll
    for (int j = 0; j < 8; ++j) {
      const int i = (rbase + j) * 32 + col;
      redsum[i] += acc[j];
    }
  }
  __syncthreads();
  reinterpret_cast<float4*>(partial + (size_t)blockIdx.x * HW)[t] =
      reinterpret_cast<const float4*>(redsum)[t];
}

// ---------------- kernel B1: reduce the SPLIT partial planes -> score planes ----------------
// grid = 128 blocks (8 per image, 128 px each), 256 threads.
__global__ __launch_bounds__(256) void pv_reduceB1(
    const float* __restrict__ partial, float* __restrict__ score)
{
  __shared__ float red[8][128];
  const int r = blockIdx.x >> 3;
  const int q = blockIdx.x & 7;
  const int t = threadIdx.x;
  const int sg = t >> 5, l32 = t & 31;
  const int px = 128 * q + 4 * l32;

  float4 a = make_float4(0.f, 0.f, 0.f, 0.f);
  #pragma unroll
  for (int i = 0; i < 8; ++i) {
    const int s = sg + 8 * i;
    const float4 v = reinterpret_cast<const float4*>(partial + ((size_t)(s * NROW + r)) * HW + px)[0];
    a.x += v.x; a.y += v.y; a.z += v.z; a.w += v.w;
  }
  *reinterpret_cast<float4*>(&red[sg][4 * l32]) = a;
  __syncthreads();
  if (t < 32) {
    float4 o = make_float4(0.f, 0.f, 0.f, 0.f);
    #pragma unroll
    for (int g = 0; g < 8; ++g) {
      const float4 v = *reinterpret_cast<const float4*>(&red[g][4 * t]);
      o.x += v.x; o.y += v.y; o.z += v.z; o.w += v.w;
    }
    *reinterpret_cast<float4*>(score + (size_t)r * HW + 128 * q + 4 * t) = o;
  }
}

// ---------------- kernel B2: exact top-20 via histogram-rank, selection, emit coords ----------------
// grid = NROW blocks, 256 threads. Output: x_out (16*96) then y_out (16*96), int32.
__global__ __launch_bounds__(256) void pv_selectB2(
    const float* __restrict__ score, int* __restrict__ out, Perm76 perm)
{
  __shared__ uint32_t hist[4096];              // 16 KB: top-12 monotone bits
  __shared__ unsigned long long keysh[HW];     //  8 KB (fallback path)
  __shared__ unsigned long long cand[256];     //  2 KB
  __shared__ int votes[KSEL];
  __shared__ int maskv[HW];
  __shared__ int wsumS[4];
  __shared__ int unsel[NUNSEL];
  __shared__ int ncand, bstarS, CtotS;

  const int r = blockIdx.x;
  const int t = threadIdx.x;
  const int lane = t & 63, wv = t >> 6;

  // 1) load scores -> monotone u32 m + full u64 keys (value | 1023-idx)
  const float4 sv4 = reinterpret_cast<const float4*>(score + (size_t)r * HW)[t];
  const float sv[4] = { sv4.x, sv4.y, sv4.z, sv4.w };
  uint32_t m[4];
  unsigned long long key[4];
  #pragma unroll
  for (int q = 0; q < 4; ++q) {
    const int i = 4 * t + q;
    const uint32_t b = __float_as_uint(sv[q]);
    m[q] = (b & 0x80000000u) ? ~b : (b | 0x80000000u);
    key[q] = ((unsigned long long)m[q] << 32) | (uint32_t)(1023 - i);
    keysh[i] = key[q];
  }
  for (int j = t; j < 4096; j += 256) hist[j] = 0;
  maskv[t] = 0; maskv[t + 256] = 0; maskv[t + 512] = 0; maskv[t + 768] = 0;
  if (t == 0) ncand = 0;
  __syncthreads();

  // 2) histogram of top-12 bits
  #pragma unroll
  for (int q = 0; q < 4; ++q) atomicAdd(&hist[m[q] >> 20], 1u);
  __syncthreads();

  // 3) suffix-scan to find threshold bin b*: suffix(b*)>=20, suffix(b*+1)<20
  uint32_t loc[16]; uint32_t tsum = 0;
  #pragma unroll
  for (int j = 0; j < 16; ++j) { loc[j] = hist[t * 16 + j]; tsum += loc[j]; }
  uint32_t ssum = tsum;
  #pragma unroll
  for (int d = 1; d < 64; d <<= 1) {
    const uint32_t o = __shfl_down(ssum, d);
    if (lane + d < 64) ssum += o;
  }
  if (lane == 0) wsumS[wv] = (int)ssum;        // wave total
  __syncthreads();
  uint32_t above = 0;
  for (int w = wv + 1; w < 4; ++w) above += (uint32_t)wsumS[w];
  uint32_t run = ssum + above - tsum;          // suffix over threads above this one
  #pragma unroll
  for (int j = 15; j >= 0; --j) {
    run += loc[j];
    if (run >= KSEL && run - loc[j] < KSEL) { bstarS = t * 16 + j; CtotS = (int)run; }
  }
  __syncthreads();
  const int bstar = bstarS, C = CtotS;

  if (C <= 256) {
    // 4a) collect candidates (all keys with top-12 >= b*), exact all-pairs rank
    #pragma unroll
    for (int q = 0; q < 4; ++q)
      if ((int)(m[q] >> 20) >= bstar) { const int p = atomicAdd(&ncand, 1); cand[p] = key[q]; }
    __syncthreads();
    if (t < C) {
      const unsigned long long my = cand[t];
      int rank = 0;
      for (int j = 0; j < C; ++j) rank += (cand[j] > my);
      if (rank < KSEL) votes[rank] = 1023 - (int)(my & 1023ull);
    }
  } else {
    // 4b) fallback: wave-0 iterative top-20 over keysh
    if (t < 64) {
      unsigned long long keys[16];
      #pragma unroll
      for (int j = 0; j < 16; ++j) keys[j] = keysh[t * 16 + j];
      for (int k = 0; k < KSEL; ++k) {
        unsigned long long best = 0ull;
        #pragma unroll
        for (int j = 0; j < 16; ++j) best = keys[j] > best ? keys[j] : best;
        #pragma unroll
        for (int off = 32; off; off >>= 1) {
          const unsigned long long o = __shfl_xor(best, off);
          if (o > best) best = o;
        }
        #pragma unroll
        for (int j = 0; j < 16; ++j) if (keys[j] == best) keys[j] = 0ull;
        if (t == 0) votes[k] = 1023 - (int)(best & 1023ull);
      }
    }
  }
  __syncthreads();

  // 5) selected coords + mask
  if (t < KSEL) {
    const int idx = votes[t];
    maskv[idx] = 1;
    int xx = idx & 31, yy = idx >> 5;
    if (xx < 1) xx = 1;
    if (yy < 1) yy = 1;
    out[r * PSEL + t]               = xx;
    out[NROW * PSEL + r * PSEL + t] = yy;
  }
  __syncthreads();

  // 6) unselected indices ascending via shfl prefix over !mask
  int cnt = 0;
  #pragma unroll
  for (int j = 0; j < 4; ++j) cnt += (maskv[t * 4 + j] == 0);
  int inc = cnt;
  #pragma unroll
  for (int d = 1; d < 64; d <<= 1) {
    const int o = __shfl_up(inc, d);
    if (lane >= d) inc += o;
  }
  if (lane == 63) wsumS[wv] = inc;
  __syncthreads();
  int basep = 0;
  for (int i = 0; i < 4; ++i) if (i < wv) basep += wsumS[i];
  int pos = basep + inc - cnt;                 // exclusive prefix
  #pragma unroll
  for (int j = 0; j < 4; ++j) {
    const int i = t * 4 + j;
    if (!maskv[i]) unsel[pos++] = i;
  }
  __syncthreads();

  // 7) random remaining via fixed permutation
  if (t < NREM) {
    const int u = unsel[perm.p[t]];
    int xx = u & 31, yy = u >> 5;
    if (xx < 1) xx = 1;
    if (yy < 1) yy = 1;
    out[r * PSEL + KSEL + t]               = xx;
    out[NROW * PSEL + r * PSEL + KSEL + t] = yy;
  }
}

// ---------------- host: JAX threefry2x32 (partitionable) ----------------
static inline uint32_t rotl32(uint32_t v, uint32_t n) { return (v << n) | (v >> (32 - n)); }

static void tf2x32(uint32_t k0, uint32_t k1, uint32_t x0, uint32_t x1,
                   uint32_t* o0, uint32_t* o1)
{
  const uint32_t ks[3] = { k0, k1, k0 ^ k1 ^ 0x1BD11BDAu };
  static const uint32_t rot[2][4] = { {13, 15, 26, 6}, {17, 29, 16, 24} };
  x0 += ks[0]; x1 += ks[1];
  for (int i = 0; i < 5; ++i) {
    const uint32_t* rr = rot[i & 1];
    for (int j = 0; j < 4; ++j) { x0 += x1; x1 = rotl32(x1, rr[j]); x1 ^= x0; }
    x0 += ks[(i + 1) % 3];
    x1 += ks[(i + 2) % 3] + (uint32_t)(i + 1);
  }
  *o0 = x0; *o1 = x1;
}

// perm = jax.random.permutation(jax.random.key(42), 1004)[:76]  (threefry_partitionable)
static void compute_perm(int* perm_out)
{
  uint32_t bits[NUNSEL];
  uint32_t sk0, sk1;
  { uint32_t o0, o1; tf2x32(0u, 42u, 0u, 1u, &o0, &o1); sk0 = o0; sk1 = o1; }
  for (int i = 0; i < NUNSEL; ++i) {
    uint32_t o0, o1; tf2x32(sk0, sk1, 0u, (uint32_t)i, &o0, &o1);
    bits[i] = o0 ^ o1;
  }
  int idx[NUNSEL];
  for (int i = 0; i < NUNSEL; ++i) idx[i] = i;
  std::stable_sort(idx, idx + NUNSEL, [&](int a, int b) { return bits[a] < bits[b]; });
  for (int j = 0; j < NREM; ++j) perm_out[j] = idx[j];
}

extern "C" void kernel_launch(void* const* d_in, const int* in_sizes, int n_in,
                              void* d_out, int out_size, void* d_ws, size_t ws_size,
                              hipStream_t stream)
{
  (void)in_sizes; (void)n_in; (void)out_size; (void)ws_size;
  const float* feat = (const float*)d_in[0];
  const float* dw_w = (const float*)d_in[1];
  // d_in[2] = dw_b (zeros; constant shift, ordering-irrelevant)
  const float* pw_w = (const float*)d_in[3];
  // d_in[4] = pw_b (constant shift, ordering-irrelevant)
  int*   out     = (int*)d_out;
  float* partial = (float*)d_ws;                       // SPLIT*NROW*HW f32 = 4 MB, fully rewritten
  float* score   = (float*)d_ws + (size_t)SPLIT * NROW * HW;  // 16*4 KB, fully rewritten

  Perm76 perm;
  compute_perm(perm.p);                                // deterministic host compute, kernel-arg baked

  pv_convA<<<NROW * SPLIT, 256, 0, stream>>>(feat, dw_w, pw_w, partial);
  pv_reduceB1<<<128, 256, 0, stream>>>(partial, score);
  pv_selectB2<<<NROW, 256, 0, stream>>>(score, out, perm);
}